// Round 7
// baseline (234.661 us; speedup 1.0000x reference)
//
#include <hip/hip_runtime.h>
#include <math.h>

#define HEADS 8
#define DIM   64
#define DK    24
#define DHK   3
#define BB    4
#define HH    128
#define WW    128
#define NN    (HH*WW)
#define QSCALE 0.125f

// ---------------------------------------------------------------------------
// K1: Sp_part[blk] = sum over this block's 128 tokens of imap[n,i]*x[n,c]
// grid 512 (4b x 128 chunks of 128 tokens), 256 threads -> 2 blocks/CU.
// ---------------------------------------------------------------------------
__global__ __launch_bounds__(256) void s_reduce(
    const float* __restrict__ imap,   // [B*N,24]
    const float* __restrict__ x,      // [B*N,64]
    float* __restrict__ Sp_part)      // [512,1536]
{
    __shared__ float part[4*1536];
    const int tid = threadIdx.x;
    const int blk = blockIdx.x;
    const int b = blk >> 7, chunk = blk & 127;
    const int w = tid >> 6, lane = tid & 63;
    const int cq = lane & 15;         // c = cq*4
    const int ig = lane >> 4;         // i = ig*6 .. +5

    const long tok0 = (long)b * NN + chunk * 128 + w * 32;
    const float* xp = x    + tok0 * 64 + cq * 4;
    const float* mp = imap + tok0 * 24 + ig * 6;

    float acc[6][4];
    #pragma unroll
    for (int r = 0; r < 6; ++r)
        #pragma unroll
        for (int q = 0; q < 4; ++q) acc[r][q] = 0.f;

    for (int t = 0; t < 32; ++t) {
        float4 xv = *(const float4*)(xp + t * 64);
        float2 m0 = *(const float2*)(mp + t * 24);
        float2 m1 = *(const float2*)(mp + t * 24 + 2);
        float2 m2 = *(const float2*)(mp + t * 24 + 4);
        float mm[6] = {m0.x, m0.y, m1.x, m1.y, m2.x, m2.y};
        #pragma unroll
        for (int r = 0; r < 6; ++r) {
            acc[r][0] += mm[r] * xv.x;
            acc[r][1] += mm[r] * xv.y;
            acc[r][2] += mm[r] * xv.z;
            acc[r][3] += mm[r] * xv.w;
        }
    }

    float* pp = part + w * 1536;
    #pragma unroll
    for (int r = 0; r < 6; ++r) {
        float4 v = {acc[r][0], acc[r][1], acc[r][2], acc[r][3]};
        *(float4*)(pp + (ig * 6 + r) * 64 + cq * 4) = v;
    }
    __syncthreads();

    for (int e = tid; e < 1536; e += 256)
        Sp_part[(long)blk * 1536 + e] =
            part[e] + part[1536 + e] + part[3072 + e] + part[4608 + e];
}

// ---------------------------------------------------------------------------
// K2: fused partial-sum + attention + P.  grid 4 blocks, 256 thr.
// 128 partials/batch, 16-wide unroll: 8 rounds x ~900cy cross-XCD latency
// with 96 loads in flight (R5 lesson: never a serial per-line chain here).
// ---------------------------------------------------------------------------
__global__ __launch_bounds__(256) void attn_fused(
    const float* __restrict__ Sp_part, // [512,1536]
    const float* __restrict__ Wk,      // [24,24]
    const float* __restrict__ Wq,      // [64,512]
    const float* __restrict__ Wv,      // [64,512]
    const float* __restrict__ rescale, // [8]
    const float* __restrict__ Wp,      // [24,24]
    float* __restrict__ Pt)            // [B,24,64]
{
    __shared__ float Sp_l[1536];
    __shared__ float S_l[1536];
    __shared__ float att[1536];
    __shared__ float M_l[1536];

    const int b = blockIdx.x, tid = threadIdx.x;

    {
        float s[6] = {0.f, 0.f, 0.f, 0.f, 0.f, 0.f};
        const float* p = Sp_part + (long)b * 128 * 1536;
        for (int c0 = 0; c0 < 128; c0 += 16) {
            float v[16][6];
            #pragma unroll
            for (int cc = 0; cc < 16; ++cc)
                #pragma unroll
                for (int k = 0; k < 6; ++k)
                    v[cc][k] = p[(long)(c0 + cc) * 1536 + tid + 256 * k];
            #pragma unroll
            for (int cc = 0; cc < 16; ++cc)
                #pragma unroll
                for (int k = 0; k < 6; ++k)
                    s[k] += v[cc][k];
        }
        #pragma unroll
        for (int k = 0; k < 6; ++k) Sp_l[tid + 256 * k] = s[k];
    }
    __syncthreads();

    for (int q = tid; q < 1536; q += 256) {
        int c = q & 63, j = q >> 6;
        float s = 0.f;
        #pragma unroll
        for (int i = 0; i < 24; ++i) s += Wk[i * 24 + j] * Sp_l[i * 64 + c];
        S_l[q] = s;
    }
    __syncthreads();

    for (int q = tid; q < 1536; q += 256) {
        int d = q & 63, ch = q >> 6;
        int h = ch / 3;
        const float* wq = Wq + h * 64 + d;
        const float* sr = S_l + ch * 64;
        float s = 0.f;
        for (int cc = 0; cc < 64; ++cc) s += sr[cc] * wq[cc * 512];
        att[q] = s * QSCALE * rescale[h];
    }
    __syncthreads();

    if (tid < 24) {
        float* row = att + tid * 64;
        float mx = row[0];
        for (int d = 1; d < 64; ++d) mx = fmaxf(mx, row[d]);
        float sum = 0.f;
        for (int d = 0; d < 64; ++d) { float e = expf(row[d] - mx); row[d] = e; sum += e; }
        float inv = 1.f / sum;
        for (int d = 0; d < 64; ++d) row[d] *= inv;
    }
    __syncthreads();

    for (int q = tid; q < 1536; q += 256) {
        int c = q & 63, ch = q >> 6;
        int h = ch / 3;
        const float* wv = Wv + c * 512 + h * 64;
        const float* ar = att + ch * 64;
        float s = 0.f;
        for (int d = 0; d < 64; ++d) s += ar[d] * wv[d];
        M_l[ch * 64 + c] = s;
    }
    __syncthreads();

    for (int q = tid; q < 1536; q += 256) {
        int c = q & 63, jo = q >> 6;
        float s = 0.f;
        #pragma unroll
        for (int k = 0; k < 3; ++k)
            #pragma unroll
            for (int h = 0; h < 8; ++h)
                s += M_l[(h * 3 + k) * 64 + c] * Wp[(k * 8 + h) * 24 + jo];
        Pt[b * 1536 + q] = s;
    }
}

// ---------------------------------------------------------------------------
// K3: y1 = gelu(gconv(imap @ Wk, c1w)) — kproj recomputed per-tile into LDS.
// 8x8 tile, 10x10 halo, 192 threads. kbuf stride 28 floats (16B-aligned).
// ---------------------------------------------------------------------------
__global__ __launch_bounds__(192, 2) void conv1_kproj_gelu(
    const float* __restrict__ imap, const float* __restrict__ Wk,
    const float* __restrict__ cw, float* __restrict__ y1)
{
    __shared__ __align__(16) float kbuf[100 * 28];

    const int tid = threadIdx.x;
    const int blk = blockIdx.x;
    const int b = blk >> 8, ti = (blk >> 4) & 15, tj = blk & 15;
    const int i0 = ti * 8, j0 = tj * 8;

    if (tid < 100) {
        const int pi = tid / 10, pj = tid % 10;
        const int gi = i0 + pi - 1, gj = j0 + pj - 1;
        float kv[24];
        #pragma unroll
        for (int j = 0; j < 24; ++j) kv[j] = 0.f;
        if (gi >= 0 && gi < HH && gj >= 0 && gj < WW) {
            const float4* m4 = (const float4*)(imap + (((long)b * HH + gi) * WW + gj) * 24);
            float m[24];
            #pragma unroll
            for (int i = 0; i < 6; ++i) {
                float4 v = m4[i];
                m[4*i+0]=v.x; m[4*i+1]=v.y; m[4*i+2]=v.z; m[4*i+3]=v.w;
            }
            for (int i = 0; i < 24; ++i) {
                float mi = m[i];
                #pragma unroll
                for (int j = 0; j < 24; ++j) kv[j] += mi * Wk[i * 24 + j];
            }
        }
        #pragma unroll
        for (int j = 0; j < 24; ++j) kbuf[tid * 28 + j] = kv[j];
    }
    __syncthreads();

    const int o = tid % 24, jj = tid / 24;   // jj 0..7
    const int g = o >> 3;

    float wr[8][9];   // wr[ic][di*3+dj], OIHW-linear
    {
        const float4* wp = (const float4*)(cw + o * 72);
        #pragma unroll
        for (int t = 0; t < 18; ++t) ((float4*)wr)[t] = wp[t];
    }

    float win[3][3][8];
    #define LROW(R, SLOT)                                                     \
    {                                                                         \
        const float* rp_ = kbuf + ((R) * 10 + jj) * 28 + g * 8;               \
        *(float4*)&win[SLOT][0][0] = *(const float4*)(rp_);                   \
        *(float4*)&win[SLOT][0][4] = *(const float4*)(rp_ + 4);               \
        *(float4*)&win[SLOT][1][0] = *(const float4*)(rp_ + 28);              \
        *(float4*)&win[SLOT][1][4] = *(const float4*)(rp_ + 32);              \
        *(float4*)&win[SLOT][2][0] = *(const float4*)(rp_ + 56);              \
        *(float4*)&win[SLOT][2][4] = *(const float4*)(rp_ + 60);              \
    }

    LROW(0, 0)
    LROW(1, 1)
    #pragma unroll
    for (int ii = 0; ii < 8; ++ii) {
        LROW(ii + 2, (ii + 2) % 3)
        float s = 0.f;
        #pragma unroll
        for (int di = 0; di < 3; ++di) {
            const int slot = (ii + di) % 3;
            #pragma unroll
            for (int dj = 0; dj < 3; ++dj)
                #pragma unroll
                for (int ic = 0; ic < 8; ++ic)
                    s += win[slot][dj][ic] * wr[ic][di * 3 + dj];
        }
        s = 0.5f * s * (1.f + erff(s * 0.70710678f));
        y1[((long)((b * HH + i0 + ii) * WW + j0)) * 24 + tid] = s;
    }
    #undef LROW
}

// ---------------------------------------------------------------------------
// K4: out = fea @ P[b] + bp + gconv(y1, c2w). 8x8 tile, 192 thr.
// ---------------------------------------------------------------------------
__global__ __launch_bounds__(192, 2) void conv2_proj(
    const float* __restrict__ y1, const float* __restrict__ fea,
    const float* __restrict__ cw2, const float* __restrict__ Pt,
    const float* __restrict__ bp, float* __restrict__ outp)
{
    const int tid = threadIdx.x;
    const int o = tid % 24, jj = tid / 24;
    const int blk = blockIdx.x;
    const int b = blk >> 8, ti = (blk >> 4) & 15, tj = blk & 15;
    const int i0 = ti * 8, j0 = tj * 8;
    const int g = o >> 3;

    float wr[8][9];
    {
        const float4* wp = (const float4*)(cw2 + o * 72);
        #pragma unroll
        for (int t = 0; t < 18; ++t) ((float4*)wr)[t] = wp[t];
    }
    const int gj0 = j0 + jj - 1;
    const bool cok0 = gj0 >= 0;
    const bool cok2 = (j0 + jj + 1) < WW;

    float acc[8];
    {
        const float bo = bp[o];
        #pragma unroll
        for (int ii = 0; ii < 8; ++ii) acc[ii] = bo;
        const float* PtRow = Pt + b * 1536 + o * 64;
        const float* feaB = fea + (((long)(b * HH + i0)) * WW + (j0 + jj)) * 64;
        for (int cq = 0; cq < 16; ++cq) {
            float4 p = *(const float4*)(PtRow + cq * 4);
            #pragma unroll
            for (int ii = 0; ii < 8; ++ii) {
                float4 f = *(const float4*)(feaB + (long)ii * WW * 64 + cq * 4);
                acc[ii] += f.x * p.x + f.y * p.y + f.z * p.z + f.w * p.w;
            }
        }
    }

    float win[3][3][8];
    #define LOADROW(GI, SLOT)                                                 \
    {                                                                         \
        const int gi_ = (GI);                                                 \
        const bool rok_ = (gi_ >= 0) & (gi_ < HH);                            \
        const float* rp_ = y1 + (long)b * NN * 24 + g * 8                     \
                         + ((long)gi_ * WW + gj0) * 24;                       \
        float4 z_ = {0.f,0.f,0.f,0.f};                                        \
        float4 a0_=z_, a1_=z_, b0_=z_, b1_=z_, c0_=z_, c1_=z_;                \
        if (rok_ & cok0) { a0_ = *(const float4*)(rp_);                       \
                           a1_ = *(const float4*)(rp_ + 4); }                 \
        if (rok_)        { b0_ = *(const float4*)(rp_ + 24);                  \
                           b1_ = *(const float4*)(rp_ + 28); }                \
        if (rok_ & cok2) { c0_ = *(const float4*)(rp_ + 48);                  \
                           c1_ = *(const float4*)(rp_ + 52); }                \
        *(float4*)&win[SLOT][0][0] = a0_; *(float4*)&win[SLOT][0][4] = a1_;   \
        *(float4*)&win[SLOT][1][0] = b0_; *(float4*)&win[SLOT][1][4] = b1_;   \
        *(float4*)&win[SLOT][2][0] = c0_; *(float4*)&win[SLOT][2][4] = c1_;   \
    }

    LOADROW(i0 - 1, 0)
    LOADROW(i0,     1)
    #pragma unroll
    for (int ii = 0; ii < 8; ++ii) {
        LOADROW(i0 + ii + 1, (ii + 2) % 3)
        float s = 0.f;
        #pragma unroll
        for (int di = 0; di < 3; ++di) {
            const int slot = (ii + di) % 3;
            #pragma unroll
            for (int dj = 0; dj < 3; ++dj)
                #pragma unroll
                for (int ic = 0; ic < 8; ++ic)
                    s += win[slot][dj][ic] * wr[ic][di * 3 + dj];
        }
        outp[((long)((b * HH + i0 + ii) * WW + j0)) * 24 + tid] = acc[ii] + s;
    }
    #undef LOADROW
}

// ---------------------------------------------------------------------------
extern "C" void kernel_launch(void* const* d_in, const int* in_sizes, int n_in,
                              void* d_out, int out_size, void* d_ws, size_t ws_size,
                              hipStream_t stream) {
    const float* x_in    = (const float*)d_in[0];
    const float* fea     = (const float*)d_in[1];
    const float* imap    = (const float*)d_in[2];
    const float* Wq      = (const float*)d_in[3];
    const float* Wk      = (const float*)d_in[4];
    const float* Wv      = (const float*)d_in[5];
    const float* rescale = (const float*)d_in[6];
    const float* Wp      = (const float*)d_in[7];
    const float* bp      = (const float*)d_in[8];
    const float* c1w     = (const float*)d_in[9];
    const float* c2w     = (const float*)d_in[10];
    float* out = (float*)d_out;

    float* ws      = (float*)d_ws;
    float* y1      = ws;                     // 1,572,864 floats
    float* Sp_part = ws + 1572864;           // 512*1536 = 786,432
    float* Pt      = ws + 2359296;           // 6144

    s_reduce<<<512, 256, 0, stream>>>(imap, x_in, Sp_part);
    attn_fused<<<4, 256, 0, stream>>>(Sp_part, Wk, Wq, Wv, rescale, Wp, Pt);
    conv1_kproj_gelu<<<BB * 256, 192, 0, stream>>>(imap, Wk, c1w, y1);
    conv2_proj<<<BB * 256, 192, 0, stream>>>(y1, fea, c2w, Pt, bp, out);
}

// Round 8
// 174.183 us; speedup vs baseline: 1.3472x; 1.3472x over previous
//
#include <hip/hip_runtime.h>
#include <math.h>

#define HEADS 8
#define DIM   64
#define DK    24
#define DHK   3
#define BB    4
#define HH    128
#define WW    128
#define NN    (HH*WW)
#define QSCALE 0.125f

// ---------------------------------------------------------------------------
// K1: Sp_part[blk] = sum over this block's 256 tokens of imap[n,i]*x[n,c]
// grid 256 (4b x 64 chunks of 256 tokens), 256 threads.
// (64 partials/batch keeps the consumer's reduction short; R6-proven.)
// ---------------------------------------------------------------------------
__global__ __launch_bounds__(256) void s_reduce(
    const float* __restrict__ imap,   // [B*N,24]
    const float* __restrict__ x,      // [B*N,64]
    float* __restrict__ Sp_part)      // [256,1536]
{
    __shared__ float part[4*1536];
    const int tid = threadIdx.x;
    const int blk = blockIdx.x;
    const int b = blk >> 6, chunk = blk & 63;
    const int w = tid >> 6, lane = tid & 63;
    const int cq = lane & 15;         // c = cq*4
    const int ig = lane >> 4;         // i = ig*6 .. +5

    const long tok0 = (long)b * NN + chunk * 256 + w * 64;
    const float* xp = x    + tok0 * 64 + cq * 4;
    const float* mp = imap + tok0 * 24 + ig * 6;

    float acc[6][4];
    #pragma unroll
    for (int r = 0; r < 6; ++r)
        #pragma unroll
        for (int q = 0; q < 4; ++q) acc[r][q] = 0.f;

    for (int t = 0; t < 64; ++t) {
        float4 xv = *(const float4*)(xp + t * 64);
        float2 m0 = *(const float2*)(mp + t * 24);
        float2 m1 = *(const float2*)(mp + t * 24 + 2);
        float2 m2 = *(const float2*)(mp + t * 24 + 4);
        float mm[6] = {m0.x, m0.y, m1.x, m1.y, m2.x, m2.y};
        #pragma unroll
        for (int r = 0; r < 6; ++r) {
            acc[r][0] += mm[r] * xv.x;
            acc[r][1] += mm[r] * xv.y;
            acc[r][2] += mm[r] * xv.z;
            acc[r][3] += mm[r] * xv.w;
        }
    }

    float* pp = part + w * 1536;
    #pragma unroll
    for (int r = 0; r < 6; ++r) {
        float4 v = {acc[r][0], acc[r][1], acc[r][2], acc[r][3]};
        *(float4*)(pp + (ig * 6 + r) * 64 + cq * 4) = v;
    }
    __syncthreads();

    for (int e = tid; e < 1536; e += 256)
        Sp_part[(long)blk * 1536 + e] =
            part[e] + part[1536 + e] + part[3072 + e] + part[4608 + e];
}

// ---------------------------------------------------------------------------
// K2: fused partial-sum + attention + P.  grid 4 blocks, 256 thr.
// 64 partials/batch, 8-wide unroll (48 live floats — fits the ~68-VGPR
// allocation; R7 lesson: 16-wide implied 96 live floats -> spill -> 2x
// slower than even the serial R5 version).
// ---------------------------------------------------------------------------
__global__ __launch_bounds__(256) void attn_fused(
    const float* __restrict__ Sp_part, // [256,1536]
    const float* __restrict__ Wk,      // [24,24]
    const float* __restrict__ Wq,      // [64,512]
    const float* __restrict__ Wv,      // [64,512]
    const float* __restrict__ rescale, // [8]
    const float* __restrict__ Wp,      // [24,24]
    float* __restrict__ Pt)            // [B,24,64]
{
    __shared__ float Sp_l[1536];
    __shared__ float S_l[1536];
    __shared__ float att[1536];
    __shared__ float M_l[1536];

    const int b = blockIdx.x, tid = threadIdx.x;

    // sum this batch's 64 chunk-partials, 8 c's per round in flight
    {
        float s[6] = {0.f, 0.f, 0.f, 0.f, 0.f, 0.f};
        const float* p = Sp_part + (long)b * 64 * 1536;
        for (int c0 = 0; c0 < 64; c0 += 8) {
            float v[8][6];
            #pragma unroll
            for (int cc = 0; cc < 8; ++cc)
                #pragma unroll
                for (int k = 0; k < 6; ++k)
                    v[cc][k] = p[(long)(c0 + cc) * 1536 + tid + 256 * k];
            #pragma unroll
            for (int cc = 0; cc < 8; ++cc)
                #pragma unroll
                for (int k = 0; k < 6; ++k)
                    s[k] += v[cc][k];
        }
        #pragma unroll
        for (int k = 0; k < 6; ++k) Sp_l[tid + 256 * k] = s[k];
    }
    __syncthreads();

    for (int q = tid; q < 1536; q += 256) {
        int c = q & 63, j = q >> 6;
        float s = 0.f;
        #pragma unroll
        for (int i = 0; i < 24; ++i) s += Wk[i * 24 + j] * Sp_l[i * 64 + c];
        S_l[q] = s;
    }
    __syncthreads();

    for (int q = tid; q < 1536; q += 256) {
        int d = q & 63, ch = q >> 6;
        int h = ch / 3;
        const float* wq = Wq + h * 64 + d;
        const float* sr = S_l + ch * 64;
        float s = 0.f;
        for (int cc = 0; cc < 64; ++cc) s += sr[cc] * wq[cc * 512];
        att[q] = s * QSCALE * rescale[h];
    }
    __syncthreads();

    if (tid < 24) {
        float* row = att + tid * 64;
        float mx = row[0];
        for (int d = 1; d < 64; ++d) mx = fmaxf(mx, row[d]);
        float sum = 0.f;
        for (int d = 0; d < 64; ++d) { float e = expf(row[d] - mx); row[d] = e; sum += e; }
        float inv = 1.f / sum;
        for (int d = 0; d < 64; ++d) row[d] *= inv;
    }
    __syncthreads();

    for (int q = tid; q < 1536; q += 256) {
        int c = q & 63, ch = q >> 6;
        int h = ch / 3;
        const float* wv = Wv + c * 512 + h * 64;
        const float* ar = att + ch * 64;
        float s = 0.f;
        for (int d = 0; d < 64; ++d) s += ar[d] * wv[d];
        M_l[ch * 64 + c] = s;
    }
    __syncthreads();

    for (int q = tid; q < 1536; q += 256) {
        int c = q & 63, jo = q >> 6;
        float s = 0.f;
        #pragma unroll
        for (int k = 0; k < 3; ++k)
            #pragma unroll
            for (int h = 0; h < 8; ++h)
                s += M_l[(h * 3 + k) * 64 + c] * Wp[(k * 8 + h) * 24 + jo];
        Pt[b * 1536 + q] = s;
    }
}

// ---------------------------------------------------------------------------
// K3: y1 = gelu(gconv(imap @ Wk, c1w)) — kproj recomputed per-tile into LDS.
// 8x8 tile, 10x10 halo, 192 threads. kbuf stride 28 floats (16B-aligned).
// ---------------------------------------------------------------------------
__global__ __launch_bounds__(192, 2) void conv1_kproj_gelu(
    const float* __restrict__ imap, const float* __restrict__ Wk,
    const float* __restrict__ cw, float* __restrict__ y1)
{
    __shared__ __align__(16) float kbuf[100 * 28];

    const int tid = threadIdx.x;
    const int blk = blockIdx.x;
    const int b = blk >> 8, ti = (blk >> 4) & 15, tj = blk & 15;
    const int i0 = ti * 8, j0 = tj * 8;

    if (tid < 100) {
        const int pi = tid / 10, pj = tid % 10;
        const int gi = i0 + pi - 1, gj = j0 + pj - 1;
        float kv[24];
        #pragma unroll
        for (int j = 0; j < 24; ++j) kv[j] = 0.f;
        if (gi >= 0 && gi < HH && gj >= 0 && gj < WW) {
            const float4* m4 = (const float4*)(imap + (((long)b * HH + gi) * WW + gj) * 24);
            float m[24];
            #pragma unroll
            for (int i = 0; i < 6; ++i) {
                float4 v = m4[i];
                m[4*i+0]=v.x; m[4*i+1]=v.y; m[4*i+2]=v.z; m[4*i+3]=v.w;
            }
            for (int i = 0; i < 24; ++i) {
                float mi = m[i];
                #pragma unroll
                for (int j = 0; j < 24; ++j) kv[j] += mi * Wk[i * 24 + j];
            }
        }
        #pragma unroll
        for (int j = 0; j < 24; ++j) kbuf[tid * 28 + j] = kv[j];
    }
    __syncthreads();

    const int o = tid % 24, jj = tid / 24;   // jj 0..7
    const int g = o >> 3;

    float wr[8][9];   // wr[ic][di*3+dj], OIHW-linear
    {
        const float4* wp = (const float4*)(cw + o * 72);
        #pragma unroll
        for (int t = 0; t < 18; ++t) ((float4*)wr)[t] = wp[t];
    }

    float win[3][3][8];
    #define LROW(R, SLOT)                                                     \
    {                                                                         \
        const float* rp_ = kbuf + ((R) * 10 + jj) * 28 + g * 8;               \
        *(float4*)&win[SLOT][0][0] = *(const float4*)(rp_);                   \
        *(float4*)&win[SLOT][0][4] = *(const float4*)(rp_ + 4);               \
        *(float4*)&win[SLOT][1][0] = *(const float4*)(rp_ + 28);              \
        *(float4*)&win[SLOT][1][4] = *(const float4*)(rp_ + 32);              \
        *(float4*)&win[SLOT][2][0] = *(const float4*)(rp_ + 56);              \
        *(float4*)&win[SLOT][2][4] = *(const float4*)(rp_ + 60);              \
    }

    LROW(0, 0)
    LROW(1, 1)
    #pragma unroll
    for (int ii = 0; ii < 8; ++ii) {
        LROW(ii + 2, (ii + 2) % 3)
        float s = 0.f;
        #pragma unroll
        for (int di = 0; di < 3; ++di) {
            const int slot = (ii + di) % 3;
            #pragma unroll
            for (int dj = 0; dj < 3; ++dj)
                #pragma unroll
                for (int ic = 0; ic < 8; ++ic)
                    s += win[slot][dj][ic] * wr[ic][di * 3 + dj];
        }
        s = 0.5f * s * (1.f + erff(s * 0.70710678f));
        y1[((long)((b * HH + i0 + ii) * WW + j0)) * 24 + tid] = s;
    }
    #undef LROW
}

// ---------------------------------------------------------------------------
// K4: out = fea @ P[b] + bp + gconv(y1, c2w). 8x8 tile, 192 thr.
// ---------------------------------------------------------------------------
__global__ __launch_bounds__(192, 2) void conv2_proj(
    const float* __restrict__ y1, const float* __restrict__ fea,
    const float* __restrict__ cw2, const float* __restrict__ Pt,
    const float* __restrict__ bp, float* __restrict__ outp)
{
    const int tid = threadIdx.x;
    const int o = tid % 24, jj = tid / 24;
    const int blk = blockIdx.x;
    const int b = blk >> 8, ti = (blk >> 4) & 15, tj = blk & 15;
    const int i0 = ti * 8, j0 = tj * 8;
    const int g = o >> 3;

    float wr[8][9];
    {
        const float4* wp = (const float4*)(cw2 + o * 72);
        #pragma unroll
        for (int t = 0; t < 18; ++t) ((float4*)wr)[t] = wp[t];
    }
    const int gj0 = j0 + jj - 1;
    const bool cok0 = gj0 >= 0;
    const bool cok2 = (j0 + jj + 1) < WW;

    float acc[8];
    {
        const float bo = bp[o];
        #pragma unroll
        for (int ii = 0; ii < 8; ++ii) acc[ii] = bo;
        const float* PtRow = Pt + b * 1536 + o * 64;
        const float* feaB = fea + (((long)(b * HH + i0)) * WW + (j0 + jj)) * 64;
        for (int cq = 0; cq < 16; ++cq) {
            float4 p = *(const float4*)(PtRow + cq * 4);
            #pragma unroll
            for (int ii = 0; ii < 8; ++ii) {
                float4 f = *(const float4*)(feaB + (long)ii * WW * 64 + cq * 4);
                acc[ii] += f.x * p.x + f.y * p.y + f.z * p.z + f.w * p.w;
            }
        }
    }

    float win[3][3][8];
    #define LOADROW(GI, SLOT)                                                 \
    {                                                                         \
        const int gi_ = (GI);                                                 \
        const bool rok_ = (gi_ >= 0) & (gi_ < HH);                            \
        const float* rp_ = y1 + (long)b * NN * 24 + g * 8                     \
                         + ((long)gi_ * WW + gj0) * 24;                       \
        float4 z_ = {0.f,0.f,0.f,0.f};                                        \
        float4 a0_=z_, a1_=z_, b0_=z_, b1_=z_, c0_=z_, c1_=z_;                \
        if (rok_ & cok0) { a0_ = *(const float4*)(rp_);                       \
                           a1_ = *(const float4*)(rp_ + 4); }                 \
        if (rok_)        { b0_ = *(const float4*)(rp_ + 24);                  \
                           b1_ = *(const float4*)(rp_ + 28); }                \
        if (rok_ & cok2) { c0_ = *(const float4*)(rp_ + 48);                  \
                           c1_ = *(const float4*)(rp_ + 52); }                \
        *(float4*)&win[SLOT][0][0] = a0_; *(float4*)&win[SLOT][0][4] = a1_;   \
        *(float4*)&win[SLOT][1][0] = b0_; *(float4*)&win[SLOT][1][4] = b1_;   \
        *(float4*)&win[SLOT][2][0] = c0_; *(float4*)&win[SLOT][2][4] = c1_;   \
    }

    LOADROW(i0 - 1, 0)
    LOADROW(i0,     1)
    #pragma unroll
    for (int ii = 0; ii < 8; ++ii) {
        LOADROW(i0 + ii + 1, (ii + 2) % 3)
        float s = 0.f;
        #pragma unroll
        for (int di = 0; di < 3; ++di) {
            const int slot = (ii + di) % 3;
            #pragma unroll
            for (int dj = 0; dj < 3; ++dj)
                #pragma unroll
                for (int ic = 0; ic < 8; ++ic)
                    s += win[slot][dj][ic] * wr[ic][di * 3 + dj];
        }
        outp[((long)((b * HH + i0 + ii) * WW + j0)) * 24 + tid] = acc[ii] + s;
    }
    #undef LOADROW
}

// ---------------------------------------------------------------------------
extern "C" void kernel_launch(void* const* d_in, const int* in_sizes, int n_in,
                              void* d_out, int out_size, void* d_ws, size_t ws_size,
                              hipStream_t stream) {
    const float* x_in    = (const float*)d_in[0];
    const float* fea     = (const float*)d_in[1];
    const float* imap    = (const float*)d_in[2];
    const float* Wq      = (const float*)d_in[3];
    const float* Wk      = (const float*)d_in[4];
    const float* Wv      = (const float*)d_in[5];
    const float* rescale = (const float*)d_in[6];
    const float* Wp      = (const float*)d_in[7];
    const float* bp      = (const float*)d_in[8];
    const float* c1w     = (const float*)d_in[9];
    const float* c2w     = (const float*)d_in[10];
    float* out = (float*)d_out;

    float* ws      = (float*)d_ws;
    float* y1      = ws;                     // 1,572,864 floats
    float* Sp_part = ws + 1572864;           // 256*1536 = 393,216
    float* Pt      = ws + 1966080;           // 6144

    s_reduce<<<256, 256, 0, stream>>>(imap, x_in, Sp_part);
    attn_fused<<<4, 256, 0, stream>>>(Sp_part, Wk, Wq, Wv, rescale, Wp, Pt);
    conv1_kproj_gelu<<<BB * 256, 192, 0, stream>>>(imap, Wk, c1w, y1);
    conv2_proj<<<BB * 256, 192, 0, stream>>>(y1, fea, c2w, Pt, bp, out);
}

// Round 9
// 174.059 us; speedup vs baseline: 1.3482x; 1.0007x over previous
//
#include <hip/hip_runtime.h>
#include <math.h>

#define HEADS 8
#define DIM   64
#define DK    24
#define DHK   3
#define BB    4
#define HH    128
#define WW    128
#define NN    (HH*WW)
#define QSCALE 0.125f

// ---------------------------------------------------------------------------
// K1: Sp_part[blk] = sum over this block's 256 tokens of imap[n,i]*x[n,c]
// grid 256 (4b x 64 chunks of 256 tokens), 256 threads.  (R6/R8-proven)
// ---------------------------------------------------------------------------
__global__ __launch_bounds__(256) void s_reduce(
    const float* __restrict__ imap,   // [B*N,24]
    const float* __restrict__ x,      // [B*N,64]
    float* __restrict__ Sp_part)      // [256,1536]
{
    __shared__ float part[4*1536];
    const int tid = threadIdx.x;
    const int blk = blockIdx.x;
    const int b = blk >> 6, chunk = blk & 63;
    const int w = tid >> 6, lane = tid & 63;
    const int cq = lane & 15;         // c = cq*4
    const int ig = lane >> 4;         // i = ig*6 .. +5

    const long tok0 = (long)b * NN + chunk * 256 + w * 64;
    const float* xp = x    + tok0 * 64 + cq * 4;
    const float* mp = imap + tok0 * 24 + ig * 6;

    float acc[6][4];
    #pragma unroll
    for (int r = 0; r < 6; ++r)
        #pragma unroll
        for (int q = 0; q < 4; ++q) acc[r][q] = 0.f;

    for (int t = 0; t < 64; ++t) {
        float4 xv = *(const float4*)(xp + t * 64);
        float2 m0 = *(const float2*)(mp + t * 24);
        float2 m1 = *(const float2*)(mp + t * 24 + 2);
        float2 m2 = *(const float2*)(mp + t * 24 + 4);
        float mm[6] = {m0.x, m0.y, m1.x, m1.y, m2.x, m2.y};
        #pragma unroll
        for (int r = 0; r < 6; ++r) {
            acc[r][0] += mm[r] * xv.x;
            acc[r][1] += mm[r] * xv.y;
            acc[r][2] += mm[r] * xv.z;
            acc[r][3] += mm[r] * xv.w;
        }
    }

    float* pp = part + w * 1536;
    #pragma unroll
    for (int r = 0; r < 6; ++r) {
        float4 v = {acc[r][0], acc[r][1], acc[r][2], acc[r][3]};
        *(float4*)(pp + (ig * 6 + r) * 64 + cq * 4) = v;
    }
    __syncthreads();

    for (int e = tid; e < 1536; e += 256)
        Sp_part[(long)blk * 1536 + e] =
            part[e] + part[1536 + e] + part[3072 + e] + part[4608 + e];
}

// ---------------------------------------------------------------------------
// K2: fused partial-sum + attention + P.  grid 4 blocks, 256 thr.
// 64 partials/batch, 8-wide unroll (48 live floats fits ~68 VGPR; R7 lesson:
// 16-wide spilled and serialized).  (R8-proven)
// ---------------------------------------------------------------------------
__global__ __launch_bounds__(256) void attn_fused(
    const float* __restrict__ Sp_part, // [256,1536]
    const float* __restrict__ Wk,      // [24,24]
    const float* __restrict__ Wq,      // [64,512]
    const float* __restrict__ Wv,      // [64,512]
    const float* __restrict__ rescale, // [8]
    const float* __restrict__ Wp,      // [24,24]
    float* __restrict__ Pt)            // [B,24,64]
{
    __shared__ float Sp_l[1536];
    __shared__ float S_l[1536];
    __shared__ float att[1536];
    __shared__ float M_l[1536];

    const int b = blockIdx.x, tid = threadIdx.x;

    {
        float s[6] = {0.f, 0.f, 0.f, 0.f, 0.f, 0.f};
        const float* p = Sp_part + (long)b * 64 * 1536;
        for (int c0 = 0; c0 < 64; c0 += 8) {
            float v[8][6];
            #pragma unroll
            for (int cc = 0; cc < 8; ++cc)
                #pragma unroll
                for (int k = 0; k < 6; ++k)
                    v[cc][k] = p[(long)(c0 + cc) * 1536 + tid + 256 * k];
            #pragma unroll
            for (int cc = 0; cc < 8; ++cc)
                #pragma unroll
                for (int k = 0; k < 6; ++k)
                    s[k] += v[cc][k];
        }
        #pragma unroll
        for (int k = 0; k < 6; ++k) Sp_l[tid + 256 * k] = s[k];
    }
    __syncthreads();

    for (int q = tid; q < 1536; q += 256) {
        int c = q & 63, j = q >> 6;
        float s = 0.f;
        #pragma unroll
        for (int i = 0; i < 24; ++i) s += Wk[i * 24 + j] * Sp_l[i * 64 + c];
        S_l[q] = s;
    }
    __syncthreads();

    for (int q = tid; q < 1536; q += 256) {
        int d = q & 63, ch = q >> 6;
        int h = ch / 3;
        const float* wq = Wq + h * 64 + d;
        const float* sr = S_l + ch * 64;
        float s = 0.f;
        for (int cc = 0; cc < 64; ++cc) s += sr[cc] * wq[cc * 512];
        att[q] = s * QSCALE * rescale[h];
    }
    __syncthreads();

    if (tid < 24) {
        float* row = att + tid * 64;
        float mx = row[0];
        for (int d = 1; d < 64; ++d) mx = fmaxf(mx, row[d]);
        float sum = 0.f;
        for (int d = 0; d < 64; ++d) { float e = expf(row[d] - mx); row[d] = e; sum += e; }
        float inv = 1.f / sum;
        for (int d = 0; d < 64; ++d) row[d] *= inv;
    }
    __syncthreads();

    for (int q = tid; q < 1536; q += 256) {
        int c = q & 63, ch = q >> 6;
        int h = ch / 3;
        const float* wv = Wv + c * 512 + h * 64;
        const float* ar = att + ch * 64;
        float s = 0.f;
        for (int d = 0; d < 64; ++d) s += ar[d] * wv[d];
        M_l[ch * 64 + c] = s;
    }
    __syncthreads();

    for (int q = tid; q < 1536; q += 256) {
        int c = q & 63, jo = q >> 6;
        float s = 0.f;
        #pragma unroll
        for (int k = 0; k < 3; ++k)
            #pragma unroll
            for (int h = 0; h < 8; ++h)
                s += M_l[(h * 3 + k) * 64 + c] * Wp[(k * 8 + h) * 24 + jo];
        Pt[b * 1536 + q] = s;
    }
}

// ---------------------------------------------------------------------------
// K3: fully fused positional branch + projection:
//   phase 1: kproj imap@Wk on 12x12 halo -> kbuf (zero outside image = SAME pad)
//   phase 2: y1 = gelu(conv1) on 10x10 -> y1l (ring outside image forced to 0)
//   phase 3: out = fea@P + bp + conv2(y1l) on 8x8
// y1 never touches global. grid 1024 x 192 thr. LDS 27.3 KB, 2 blocks/CU.
// ---------------------------------------------------------------------------
__global__ __launch_bounds__(192, 2) void conv_fused(
    const float* __restrict__ imap, const float* __restrict__ Wk,
    const float* __restrict__ c1w,  const float* __restrict__ fea,
    const float* __restrict__ c2w,  const float* __restrict__ Pt,
    const float* __restrict__ bp,   float* __restrict__ outp)
{
    __shared__ __align__(16) float kbuf[144 * 28];  // 12x12 halo, stride 28
    __shared__ __align__(16) float y1l[100 * 28];   // 10x10, stride 28

    const int tid = threadIdx.x;
    const int blk = blockIdx.x;
    const int b = blk >> 8, ti = (blk >> 4) & 15, tj = blk & 15;
    const int i0 = ti * 8, j0 = tj * 8;
    const int o = tid % 24, jj = tid / 24;   // o: out-channel; jj: 0..7
    const int g = o >> 3;

    // ---- phase 1: kproj on the 12x12 halo (threads 0..143) ----
    if (tid < 144) {
        const int pi = tid / 12, pj = tid % 12;
        const int gi = i0 + pi - 2, gj = j0 + pj - 2;
        float kv[24];
        #pragma unroll
        for (int j = 0; j < 24; ++j) kv[j] = 0.f;
        if (gi >= 0 && gi < HH && gj >= 0 && gj < WW) {
            const float4* m4 = (const float4*)(imap + (((long)b * HH + gi) * WW + gj) * 24);
            float m[24];
            #pragma unroll
            for (int i = 0; i < 6; ++i) {
                float4 v = m4[i];
                m[4*i+0]=v.x; m[4*i+1]=v.y; m[4*i+2]=v.z; m[4*i+3]=v.w;
            }
            for (int i = 0; i < 24; ++i) {
                float mi = m[i];
                #pragma unroll
                for (int j = 0; j < 24; ++j) kv[j] += mi * Wk[i * 24 + j];
            }
        }
        #pragma unroll
        for (int j = 0; j < 24; ++j) kbuf[tid * 28 + j] = kv[j];
    }
    __syncthreads();

    // ---- phase 2: y1 = gelu(conv1) on 10x10 -> y1l ----
    // 240 row-tasks (10 rows x 24 o); thread t takes task t (and t+192 if <240).
    // task o == tid%24 for both, so wr (c1w weights) loads once.
    {
        float wr[8][9];   // wr[ic][di*3+dj], OIHW-linear
        {
            const float4* wp = (const float4*)(c1w + o * 72);
            #pragma unroll
            for (int t = 0; t < 18; ++t) ((float4*)wr)[t] = wp[t];
        }
        for (int task = tid; task < 240; task += 192) {
            const int r = task / 24;           // y1l row 0..9
            float wc[3][3][8];                 // [col slot][di][ic]
            #pragma unroll
            for (int slot = 0; slot < 2; ++slot)
                #pragma unroll
                for (int di = 0; di < 3; ++di) {
                    const float* p = kbuf + ((r + di) * 12 + slot) * 28 + g * 8;
                    *(float4*)&wc[slot][di][0] = *(const float4*)(p);
                    *(float4*)&wc[slot][di][4] = *(const float4*)(p + 4);
                }
            #pragma unroll
            for (int c = 0; c < 10; ++c) {
                const int s2 = (c + 2) % 3;
                #pragma unroll
                for (int di = 0; di < 3; ++di) {
                    const float* p = kbuf + ((r + di) * 12 + (c + 2)) * 28 + g * 8;
                    *(float4*)&wc[s2][di][0] = *(const float4*)(p);
                    *(float4*)&wc[s2][di][4] = *(const float4*)(p + 4);
                }
                float s = 0.f;
                #pragma unroll
                for (int dj = 0; dj < 3; ++dj) {
                    const int sl = (c + dj) % 3;
                    #pragma unroll
                    for (int di = 0; di < 3; ++di)
                        #pragma unroll
                        for (int ic = 0; ic < 8; ++ic)
                            s += wc[sl][di][ic] * wr[ic][di * 3 + dj];
                }
                const int gi = i0 + r - 1, gj = j0 + c - 1;
                float val = 0.f;
                if (gi >= 0 && gi < HH && gj >= 0 && gj < WW)
                    val = 0.5f * s * (1.f + erff(s * 0.70710678f));
                y1l[(r * 10 + c) * 28 + o] = val;
            }
        }
    }
    __syncthreads();

    // ---- phase 3: out = fea@P + bp + conv2(y1l) on 8x8 ----
    float wr[8][9];
    {
        const float4* wp = (const float4*)(c2w + o * 72);
        #pragma unroll
        for (int t = 0; t < 18; ++t) ((float4*)wr)[t] = wp[t];
    }

    float acc[8];
    {
        const float bo = bp[o];
        #pragma unroll
        for (int ii = 0; ii < 8; ++ii) acc[ii] = bo;
        const float* PtRow = Pt + b * 1536 + o * 64;
        const float* feaB = fea + (((long)(b * HH + i0)) * WW + (j0 + jj)) * 64;
        for (int cq = 0; cq < 16; ++cq) {
            float4 p = *(const float4*)(PtRow + cq * 4);
            #pragma unroll
            for (int ii = 0; ii < 8; ++ii) {
                float4 f = *(const float4*)(feaB + (long)ii * WW * 64 + cq * 4);
                acc[ii] += f.x * p.x + f.y * p.y + f.z * p.z + f.w * p.w;
            }
        }
    }

    float win[3][3][8];   // [row slot][dj][ic]
    #define LROW(R, SLOT)                                                     \
    {                                                                         \
        const float* rp_ = y1l + ((R) * 10 + jj) * 28 + g * 8;                \
        *(float4*)&win[SLOT][0][0] = *(const float4*)(rp_);                   \
        *(float4*)&win[SLOT][0][4] = *(const float4*)(rp_ + 4);               \
        *(float4*)&win[SLOT][1][0] = *(const float4*)(rp_ + 28);              \
        *(float4*)&win[SLOT][1][4] = *(const float4*)(rp_ + 32);              \
        *(float4*)&win[SLOT][2][0] = *(const float4*)(rp_ + 56);              \
        *(float4*)&win[SLOT][2][4] = *(const float4*)(rp_ + 60);              \
    }

    LROW(0, 0)
    LROW(1, 1)
    #pragma unroll
    for (int ii = 0; ii < 8; ++ii) {
        LROW(ii + 2, (ii + 2) % 3)
        float s = 0.f;
        #pragma unroll
        for (int di = 0; di < 3; ++di) {
            const int slot = (ii + di) % 3;
            #pragma unroll
            for (int dj = 0; dj < 3; ++dj)
                #pragma unroll
                for (int ic = 0; ic < 8; ++ic)
                    s += win[slot][dj][ic] * wr[ic][di * 3 + dj];
        }
        outp[((long)((b * HH + i0 + ii) * WW + j0)) * 24 + tid] = acc[ii] + s;
    }
    #undef LROW
}

// ---------------------------------------------------------------------------
extern "C" void kernel_launch(void* const* d_in, const int* in_sizes, int n_in,
                              void* d_out, int out_size, void* d_ws, size_t ws_size,
                              hipStream_t stream) {
    const float* x_in    = (const float*)d_in[0];
    const float* fea     = (const float*)d_in[1];
    const float* imap    = (const float*)d_in[2];
    const float* Wq      = (const float*)d_in[3];
    const float* Wk      = (const float*)d_in[4];
    const float* Wv      = (const float*)d_in[5];
    const float* rescale = (const float*)d_in[6];
    const float* Wp      = (const float*)d_in[7];
    const float* bp      = (const float*)d_in[8];
    const float* c1w     = (const float*)d_in[9];
    const float* c2w     = (const float*)d_in[10];
    float* out = (float*)d_out;

    float* ws      = (float*)d_ws;
    float* Sp_part = ws;                     // 256*1536 = 393,216 floats
    float* Pt      = ws + 393216;            // 6144 floats

    s_reduce<<<256, 256, 0, stream>>>(imap, x_in, Sp_part);
    attn_fused<<<4, 256, 0, stream>>>(Sp_part, Wk, Wq, Wv, rescale, Wp, Pt);
    conv_fused<<<BB * 256, 192, 0, stream>>>(imap, Wk, c1w, fea, c2w, Pt, bp, out);
}